// Round 4
// baseline (931.958 us; speedup 1.0000x reference)
//
#include <hip/hip_runtime.h>
#include <hip/hip_bf16.h>

#define Bb 32
#define Ss 2048
#define Kk 1024   // 2*EH = 2*DH
#define Aa 512

#define BM 128
#define BK 32
#define NT (Kk / BK)          // 32 K-steps
#define ABUF (BM * BK * 2)    // 8 KB bf16, layout [ks][row] 16B chunks
#define BBUF (Aa * BK * 2)    // 32 KB bf16, octet-major

typedef __bf16 bf16x8 __attribute__((ext_vector_type(8)));
typedef float f32x4 __attribute__((ext_vector_type(4)));
typedef float f32x8 __attribute__((ext_vector_type(8)));

__device__ __forceinline__ unsigned short f2bf(float f) {
  unsigned u = __float_as_uint(f);
  u += 0x7FFFu + ((u >> 16) & 1u);   // RNE
  return (unsigned short)(u >> 16);
}

__device__ __forceinline__ float tanh_fast(float x) {
  float e = __expf(2.f * x);
  return (e - 1.f) / (e + 1.f);
}

__device__ __forceinline__ void gll16(const void* g, void* l) {
  __builtin_amdgcn_global_load_lds(
      (const __attribute__((address_space(1))) unsigned int*)g,
      (__attribute__((address_space(3))) unsigned int*)l, 16, 0, 0);
}

// ---- prep: WtT[t][g][a] = 16B chunk of bf16 W[t*32+g*8+j][a], j=0..7 ----
// Exact LDS image for K-step t: B LDS addr = g*8192 + a*16.
__global__ __launch_bounds__(256) void prep_wt(const float* __restrict__ W,
                                               unsigned short* __restrict__ WtT) {
  const int idx = blockIdx.x * 256 + threadIdx.x;   // 65536
  const int a = idx & 511;
  const int o = idx >> 9;            // octet 0..127
  const int t = o >> 2, g = o & 3;
  const int k0 = o * 8;
  unsigned short u[8];
#pragma unroll
  for (int j = 0; j < 8; ++j) u[j] = f2bf(W[(size_t)(k0 + j) * Aa + a]);
  uint4 pk;
  pk.x = (unsigned)u[0] | ((unsigned)u[1] << 16);
  pk.y = (unsigned)u[2] | ((unsigned)u[3] << 16);
  pk.z = (unsigned)u[4] | ((unsigned)u[5] << 16);
  pk.w = (unsigned)u[6] | ((unsigned)u[7] << 16);
  *(uint4*)((char*)WtT + (size_t)t * 32768 + g * 8192 + a * 16) = pk;
}

// ---- temp2 = [dh0|dh1] @ U ----
__global__ __launch_bounds__(256) void t2_partial(const float* __restrict__ dh,
                                                  const float* __restrict__ U,
                                                  float* __restrict__ part) {
  const int b = blockIdx.x, kc = blockIdx.y, t = threadIdx.x;  // (32, 8)
  __shared__ float sdh[128];
  if (t < 128) {
    int k = kc * 128 + t;
    sdh[t] = dh[(k >> 9) * (Bb * 512) + b * 512 + (k & 511)];
  }
  __syncthreads();
#pragma unroll
  for (int h = 0; h < 2; ++h) {
    const int a = h * 256 + t;
    float s = 0.f;
#pragma unroll 8
    for (int kk = 0; kk < 128; ++kk) s += sdh[kk] * U[(size_t)(kc * 128 + kk) * Aa + a];
    part[(size_t)(b * 8 + kc) * Aa + a] = s;
  }
}

__global__ __launch_bounds__(256) void t2_reduce(const float* __restrict__ part,
                                                 float* __restrict__ t2) {
  const int idx = blockIdx.x * 256 + threadIdx.x;  // 16384
  const int b = idx >> 9, a = idx & 511;
  float s = 0.f;
#pragma unroll
  for (int kc = 0; kc < 8; ++kc) s += part[(size_t)(b * 8 + kc) * Aa + a];
  t2[idx] = s;
}

// ---- main: scores = tanh(enc@W + t2) @ v ----
// 80KB LDS -> 2 blocks/CU. A: global->reg->bf16->ds_write (2-deep in regs).
// B: global_load_lds (2-deep). Counted vmcnt(6) steady state, raw barriers.
#define ITER(curA, curB, nxtA, AO0, AO1, AN0, AN1, T)                           \
  {                                                                             \
    if ((T) + 2 < NT) {                                                         \
      const float* ap = aG + ((T) + 2) * BK;                                    \
      AN0 = *(const float4*)(ap);                                               \
      AN1 = *(const float4*)(ap + 4);                                           \
    }                                                                           \
    bf16x8 af[4], bfr[8];                                                       \
    _Pragma("unroll")                                                           \
    for (int mi = 0; mi < 4; ++mi) {                                            \
      const int r = wy * 64 + mi * 16 + (lane & 15);                            \
      af[mi] = *(const bf16x8*)((curA) + (lane >> 4) * 2048 + r * 16);          \
    }                                                                           \
    _Pragma("unroll")                                                           \
    for (int ni = 0; ni < 8; ++ni) {                                            \
      const int a = wx * 128 + ni * 16 + (lane & 15);                           \
      bfr[ni] = *(const bf16x8*)((curB) + (lane >> 4) * 8192 + a * 16);         \
    }                                                                           \
    __builtin_amdgcn_s_setprio(1);                                              \
    _Pragma("unroll")                                                           \
    for (int mi = 0; mi < 4; ++mi)                                              \
      _Pragma("unroll")                                                         \
      for (int ni = 0; ni < 8; ++ni)                                            \
        acc[mi][ni] = __builtin_amdgcn_mfma_f32_16x16x32_bf16(af[mi], bfr[ni], acc[mi][ni], 0, 0, 0); \
    __builtin_amdgcn_s_setprio(0);                                              \
    __builtin_amdgcn_sched_barrier(0);                                          \
    __builtin_amdgcn_s_barrier();   /* all waves done reading cur bufs */       \
    if ((T) + 2 < NT) {                                                         \
      const char* wb = wtB + (size_t)((T) + 2) * 32768;                         \
      gll16(wb + b_off0, (curB) + b_off0);                                      \
      gll16(wb + b_off1, (curB) + b_off1);                                      \
      gll16(wb + b_off2, (curB) + b_off2);                                      \
      gll16(wb + b_off3, (curB) + b_off3);                                      \
    }                                                                           \
    if ((T) < NT - 2) {                                                         \
      asm volatile("s_waitcnt vmcnt(6)" ::: "memory");                          \
    } else {                                                                    \
      asm volatile("s_waitcnt vmcnt(0)" ::: "memory");                          \
    }                                                                           \
    __builtin_amdgcn_sched_barrier(0);                                          \
    if ((T) + 1 < NT) {                                                         \
      f32x8 w8 = {AO0.x, AO0.y, AO0.z, AO0.w, AO1.x, AO1.y, AO1.z, AO1.w};      \
      *(bf16x8*)((nxtA) + a_wb) = __builtin_convertvector(w8, bf16x8);          \
    }                                                                           \
    asm volatile("s_waitcnt lgkmcnt(0)" ::: "memory");                          \
    __builtin_amdgcn_sched_barrier(0);                                          \
    __builtin_amdgcn_s_barrier();   /* publish tile T+1 */                      \
  }

__global__ __launch_bounds__(512, 4) void score_gemm(const float* __restrict__ enc,
                                                     const unsigned short* __restrict__ WtT,
                                                     const float* __restrict__ t2,
                                                     const float* __restrict__ v,
                                                     float* __restrict__ score) {
  __shared__ __align__(16) char lds[2 * (ABUF + BBUF)];   // 80 KB -> 2 blocks/CU
  char* sA0 = lds;
  char* sA1 = lds + ABUF;
  char* sB0 = lds + 2 * ABUF;
  char* sB1 = lds + 2 * ABUF + BBUF;

  const int blk = blockIdx.x;               // 512 blocks
  const int b = blk >> 4, sc = blk & 15;
  const float* encF = enc + (size_t)(b * Ss + sc * BM) * Kk;
  const char* wtB = (const char*)WtT;

  const int tid = threadIdx.x;
  const int lane = tid & 63;
  const int wid = tid >> 6;
  const int wy = wid >> 2, wx = wid & 3;    // 2 x 4 waves, wave tile 64x128

  // A staging: thread handles chunk (row = tid>>2, ks = tid&3):
  //   global 32B at row*Kk + T*BK + ks*8 floats -> 8 bf16 -> LDS ks*2048 + row*16
  const int a_row = tid >> 2;
  const int a_ks = tid & 3;
  const float* aG = encF + (size_t)a_row * Kk + a_ks * 8;
  const int a_wb = a_ks * 2048 + a_row * 16;

  // B gll offsets (identical source/dest, image pre-built by prep_wt)
  const int b_off0 = tid * 16;
  const int b_off1 = (512 + tid) * 16;
  const int b_off2 = (1024 + tid) * 16;
  const int b_off3 = (1536 + tid) * 16;

  const f32x4 zero = {0.f, 0.f, 0.f, 0.f};
  f32x4 acc[4][8];
#pragma unroll
  for (int i = 0; i < 4; ++i)
#pragma unroll
    for (int j = 0; j < 8; ++j) acc[i][j] = zero;

  float4 aO0, aO1, aN0, aN1;

  // ---- prologue: A(0)->regs, B(0) gll, A(1)->regs, B(1) gll ----
  {
    float4 p00 = *(const float4*)(aG);
    float4 p01 = *(const float4*)(aG + 4);
    gll16(wtB + b_off0, sB0 + b_off0);
    gll16(wtB + b_off1, sB0 + b_off1);
    gll16(wtB + b_off2, sB0 + b_off2);
    gll16(wtB + b_off3, sB0 + b_off3);
    aO0 = *(const float4*)(aG + BK);
    aO1 = *(const float4*)(aG + BK + 4);
    const char* wb1 = wtB + 32768;
    gll16(wb1 + b_off0, sB1 + b_off0);
    gll16(wb1 + b_off1, sB1 + b_off1);
    gll16(wb1 + b_off2, sB1 + b_off2);
    gll16(wb1 + b_off3, sB1 + b_off3);
    // write A(0)
    f32x8 w8 = {p00.x, p00.y, p00.z, p00.w, p01.x, p01.y, p01.z, p01.w};
    *(bf16x8*)(sA0 + a_wb) = __builtin_convertvector(w8, bf16x8);
    // drain B(0) (leaves A(1) 2 + B(1) 4 in flight)
    asm volatile("s_waitcnt vmcnt(6)" ::: "memory");
    asm volatile("s_waitcnt lgkmcnt(0)" ::: "memory");
    __builtin_amdgcn_sched_barrier(0);
    __builtin_amdgcn_s_barrier();
  }

  for (int t = 0; t < NT; t += 2) {
    ITER(sA0, sB0, sA1, aO0, aO1, aN0, aN1, t)
    ITER(sA1, sB1, sA0, aN0, aN1, aO0, aO1, t + 1)
  }

  // ---- epilogue: score_row += tanh(acc + t2[col]) * v[col] ----
  float t2v[8], vv[8];
#pragma unroll
  for (int ni = 0; ni < 8; ++ni) {
    int c = wx * 128 + ni * 16 + (lane & 15);
    t2v[ni] = t2[b * Aa + c];
    vv[ni] = v[c];
  }
  float sp[4][4];
#pragma unroll
  for (int mi = 0; mi < 4; ++mi)
#pragma unroll
    for (int j = 0; j < 4; ++j) sp[mi][j] = 0.f;
#pragma unroll
  for (int mi = 0; mi < 4; ++mi)
#pragma unroll
    for (int ni = 0; ni < 8; ++ni)
#pragma unroll
      for (int j = 0; j < 4; ++j) {
        float x = acc[mi][ni][j] + t2v[ni];
        sp[mi][j] += vv[ni] * tanh_fast(x);
      }

  // C/D layout: col = lane&15, row = (lane>>4)*4 + j. Reduce over 16 col-lanes.
  float* sbuf = (float*)lds;
#pragma unroll
  for (int mi = 0; mi < 4; ++mi)
#pragma unroll
    for (int j = 0; j < 4; ++j) {
      float s = sp[mi][j];
      s += __shfl_xor(s, 1);
      s += __shfl_xor(s, 2);
      s += __shfl_xor(s, 4);
      s += __shfl_xor(s, 8);
      if ((lane & 15) == 0) {
        int r = wy * 64 + mi * 16 + ((lane >> 4) << 2) + j;
        sbuf[r * 4 + wx] = s;
      }
    }
  __syncthreads();
  if (tid < BM) {
    float s = sbuf[tid * 4] + sbuf[tid * 4 + 1] + sbuf[tid * 4 + 2] + sbuf[tid * 4 + 3];
    score[b * Ss + sc * BM + tid] = s;
  }
}

// ---- softmax over S, in place in d_out's attention region ----
__global__ __launch_bounds__(256) void softmax_k(float* __restrict__ aw) {
  const int b = blockIdx.x, t = threadIdx.x;
  __shared__ float red[8];
  float s[8];
  float m = -3.4e38f;
#pragma unroll
  for (int i = 0; i < 8; ++i) {
    s[i] = aw[b * Ss + t + i * 256];
    m = fmaxf(m, s[i]);
  }
#pragma unroll
  for (int off = 1; off < 64; off <<= 1) m = fmaxf(m, __shfl_xor(m, off));
  const int lane = t & 63, wv = t >> 6;
  if (lane == 0) red[wv] = m;
  __syncthreads();
  m = fmaxf(fmaxf(red[0], red[1]), fmaxf(red[2], red[3]));
  float e[8];
  float l = 0.f;
#pragma unroll
  for (int i = 0; i < 8; ++i) { e[i] = __expf(s[i] - m); l += e[i]; }
#pragma unroll
  for (int off = 1; off < 64; off <<= 1) l += __shfl_xor(l, off);
  if (lane == 0) red[4 + wv] = l;
  __syncthreads();
  l = red[4] + red[5] + red[6] + red[7];
  const float inv = 1.f / l;
#pragma unroll
  for (int i = 0; i < 8; ++i) aw[b * Ss + t + i * 256] = e[i] * inv;
}

// ---- context = sum_s aw[s] * enc[b,s,:] ----
__global__ __launch_bounds__(256) void ctx_partial(const float* __restrict__ enc,
                                                   const float* __restrict__ aw,
                                                   float* __restrict__ part) {
  const int b = blockIdx.x, ch = blockIdx.y, t = threadIdx.x;  // (32, 32)
  __shared__ float sw[64];
  const int s0 = ch * 64;
  if (t < 64) sw[t] = aw[b * Ss + s0 + t];
  __syncthreads();
  float ax = 0.f, ay = 0.f, az = 0.f, aww = 0.f;
  const float* ebase = enc + (size_t)(b * Ss + s0) * Kk + t * 4;
#pragma unroll 4
  for (int r = 0; r < 64; ++r) {
    const float4 ev = *(const float4*)(ebase + (size_t)r * Kk);
    const float w = sw[r];
    ax += w * ev.x; ay += w * ev.y; az += w * ev.z; aww += w * ev.w;
  }
  float4 o; o.x = ax; o.y = ay; o.z = az; o.w = aww;
  *(float4*)(part + (size_t)(b * 32 + ch) * Kk + t * 4) = o;
}

__global__ __launch_bounds__(256) void ctx_reduce(const float* __restrict__ part,
                                                  float* __restrict__ ctx) {
  const int idx = blockIdx.x * 256 + threadIdx.x;   // 32768
  const int b = idx >> 10, e = idx & 1023;
  float s = 0.f;
#pragma unroll
  for (int ch = 0; ch < 32; ++ch) s += part[(size_t)(b * 32 + ch) * Kk + e];
  ctx[idx] = s;
}

extern "C" void kernel_launch(void* const* d_in, const int* in_sizes, int n_in,
                              void* d_out, int out_size, void* d_ws, size_t ws_size,
                              hipStream_t stream) {
  const float* dh  = (const float*)d_in[0];   // (2, 32, 512)
  const float* enc = (const float*)d_in[1];   // (32, 2048, 1024)
  const float* W   = (const float*)d_in[2];   // (1024, 512)
  const float* U   = (const float*)d_in[3];   // (1024, 512)
  const float* v   = (const float*)d_in[4];   // (512, 1)

  float* out_ctx = (float*)d_out;             // (32, 1, 1024) = 32768
  float* out_aw  = (float*)d_out + 32768;     // (32, 2048)    = 65536

  char* ws = (char*)d_ws;
  unsigned short* WtT = (unsigned short*)ws;                // 1 MB (octet-major)
  float* t2p   = (float*)(ws + 1048576);                    // 512 KB
  float* t2    = (float*)(ws + 1048576 + 524288);           // 64 KB
  float* cpart = (float*)(ws + 1048576 + 524288 + 65536);   // 4 MB

  prep_wt<<<256, 256, 0, stream>>>(W, WtT);
  t2_partial<<<dim3(32, 8), 256, 0, stream>>>(dh, U, t2p);
  t2_reduce<<<64, 256, 0, stream>>>(t2p, t2);
  score_gemm<<<512, 512, 0, stream>>>(enc, WtT, t2, v, out_aw);
  softmax_k<<<32, 256, 0, stream>>>(out_aw);
  ctx_partial<<<dim3(32, 32), 256, 0, stream>>>(enc, out_aw, cpart);
  ctx_reduce<<<128, 256, 0, stream>>>(cpart, out_ctx);
}

// Round 5
// 169.459 us; speedup vs baseline: 5.4996x; 5.4996x over previous
//
#include <hip/hip_runtime.h>
#include <hip/hip_bf16.h>

#define Bb 32
#define Ss 2048
#define Kk 1024   // 2*EH = 2*DH
#define Aa 512

#define BM 128
#define BK 32
#define NT (Kk / BK)          // 32 K-steps
#define ABUF (BM * BK * 4)    // 16 KB fp32
#define BBUF (Aa * BK * 2)    // 32 KB bf16

typedef __bf16 bf16x8 __attribute__((ext_vector_type(8)));
typedef float f32x4 __attribute__((ext_vector_type(4)));
typedef float f32x8 __attribute__((ext_vector_type(8)));

__device__ __forceinline__ unsigned short f2bf(float f) {
  unsigned u = __float_as_uint(f);
  u += 0x7FFFu + ((u >> 16) & 1u);   // RNE
  return (unsigned short)(u >> 16);
}

__device__ __forceinline__ float tanh_fast(float x) {
  float e = __expf(2.f * x);
  return (e - 1.f) / (e + 1.f);
}

__device__ __forceinline__ void gll16(const void* g, void* l) {
  __builtin_amdgcn_global_load_lds(
      (const __attribute__((address_space(1))) unsigned int*)g,
      (__attribute__((address_space(3))) unsigned int*)l, 16, 0, 0);
}

// ---- prep: WtT[t][g][a] = 16B chunk of bf16 W[t*32+g*8+j][a], j=0..7 ----
// Exact LDS image for K-step t: B LDS addr = g*8192 + a*16.
__global__ __launch_bounds__(256) void prep_wt(const float* __restrict__ W,
                                               unsigned short* __restrict__ WtT) {
  const int idx = blockIdx.x * 256 + threadIdx.x;   // 65536
  const int a = idx & 511;
  const int o = idx >> 9;            // octet 0..127
  const int t = o >> 2, g = o & 3;
  const int k0 = o * 8;
  unsigned short u[8];
#pragma unroll
  for (int j = 0; j < 8; ++j) u[j] = f2bf(W[(size_t)(k0 + j) * Aa + a]);
  uint4 pk;
  pk.x = (unsigned)u[0] | ((unsigned)u[1] << 16);
  pk.y = (unsigned)u[2] | ((unsigned)u[3] << 16);
  pk.z = (unsigned)u[4] | ((unsigned)u[5] << 16);
  pk.w = (unsigned)u[6] | ((unsigned)u[7] << 16);
  *(uint4*)((char*)WtT + (size_t)t * 32768 + g * 8192 + a * 16) = pk;
}

// ---- temp2 = [dh0|dh1] @ U ----
__global__ __launch_bounds__(256) void t2_partial(const float* __restrict__ dh,
                                                  const float* __restrict__ U,
                                                  float* __restrict__ part) {
  const int b = blockIdx.x, kc = blockIdx.y, t = threadIdx.x;  // (32, 8)
  __shared__ float sdh[128];
  if (t < 128) {
    int k = kc * 128 + t;
    sdh[t] = dh[(k >> 9) * (Bb * 512) + b * 512 + (k & 511)];
  }
  __syncthreads();
#pragma unroll
  for (int h = 0; h < 2; ++h) {
    const int a = h * 256 + t;
    float s = 0.f;
#pragma unroll 8
    for (int kk = 0; kk < 128; ++kk) s += sdh[kk] * U[(size_t)(kc * 128 + kk) * Aa + a];
    part[(size_t)(b * 8 + kc) * Aa + a] = s;
  }
}

__global__ __launch_bounds__(256) void t2_reduce(const float* __restrict__ part,
                                                 float* __restrict__ t2) {
  const int idx = blockIdx.x * 256 + threadIdx.x;  // 16384
  const int b = idx >> 9, a = idx & 511;
  float s = 0.f;
#pragma unroll
  for (int kc = 0; kc < 8; ++kc) s += part[(size_t)(b * 8 + kc) * Aa + a];
  t2[idx] = s;
}

// ---- main: scores = tanh(enc@W + t2) @ v ----
// Depth-3 all-gll pipeline (3 LDS buffer sets, 144 KB), counted vmcnt(12)
// steady state, raw barriers, 2-way-free A swizzle.
#define ITER(curA, curB, T, X)                                                  \
  {                                                                             \
    bf16x8 af[4], bfr[8];                                                       \
    _Pragma("unroll")                                                           \
    for (int mi = 0; mi < 4; ++mi) {                                            \
      const int rr = wy * 64 + mi * 16 + (lane & 15);                           \
      const int s0 = (lane >> 4) * 2;                                           \
      f32x4 lo = *(const f32x4*)((curA) + rr * 128 + (((s0) ^ (rr & 7)) << 4)); \
      f32x4 hi = *(const f32x4*)((curA) + rr * 128 + (((s0 + 1) ^ (rr & 7)) << 4)); \
      f32x8 w8 = {lo.x, lo.y, lo.z, lo.w, hi.x, hi.y, hi.z, hi.w};              \
      af[mi] = __builtin_convertvector(w8, bf16x8);                             \
    }                                                                           \
    _Pragma("unroll")                                                           \
    for (int ni = 0; ni < 8; ++ni) {                                            \
      const int a = wx * 128 + ni * 16 + (lane & 15);                           \
      bfr[ni] = *(const bf16x8*)((curB) + (lane >> 4) * 8192 + a * 16);         \
    }                                                                           \
    __builtin_amdgcn_s_setprio(1);                                              \
    _Pragma("unroll")                                                           \
    for (int mi = 0; mi < 4; ++mi)                                              \
      _Pragma("unroll")                                                         \
      for (int ni = 0; ni < 8; ++ni)                                            \
        acc[mi][ni] = __builtin_amdgcn_mfma_f32_16x16x32_bf16(af[mi], bfr[ni], acc[mi][ni], 0, 0, 0); \
    __builtin_amdgcn_s_setprio(0);                                              \
    __builtin_amdgcn_sched_barrier(0);                                          \
    __builtin_amdgcn_s_barrier();   /* all waves done reading cur bufs */       \
    if ((T) + 3 < NT) {                                                         \
      const char* wb = wtB + (size_t)((T) + 3) * 32768;                         \
      gll16(wb + b_off0, (curB) + b_off0);                                      \
      gll16(wb + b_off1, (curB) + b_off1);                                      \
      gll16(wb + b_off2, (curB) + b_off2);                                      \
      gll16(wb + b_off3, (curB) + b_off3);                                      \
      const char* eb = encB + ((T) + 3) * 128;                                  \
      gll16(eb + a_goff0, (curA) + a_loff0);                                    \
      gll16(eb + a_goff1, (curA) + a_loff1);                                    \
    }                                                                           \
    asm volatile("s_waitcnt vmcnt(" #X ")" ::: "memory");                       \
    __builtin_amdgcn_sched_barrier(0);                                          \
    __builtin_amdgcn_s_barrier();   /* tile T+1 published */                    \
  }

__global__ __launch_bounds__(512) void score_gemm(const float* __restrict__ enc,
                                                  const unsigned short* __restrict__ WtT,
                                                  const float* __restrict__ t2,
                                                  const float* __restrict__ v,
                                                  float* __restrict__ score) {
  __shared__ __align__(16) char lds[3 * (ABUF + BBUF)];   // 144 KB
  char* sA0 = lds;
  char* sA1 = lds + ABUF;
  char* sA2 = lds + 2 * ABUF;
  char* sB0 = lds + 3 * ABUF;
  char* sB1 = lds + 3 * ABUF + BBUF;
  char* sB2 = lds + 3 * ABUF + 2 * BBUF;

  const int blk = blockIdx.x;               // 512 blocks
  const int b = blk >> 4, sc = blk & 15;
  const char* encB = (const char*)(enc + (size_t)(b * Ss + sc * BM) * Kk);
  const char* wtB = (const char*)WtT;

  const int tid = threadIdx.x;
  const int lane = tid & 63;
  const int wid = tid >> 6;
  const int wy = wid >> 2, wx = wid & 3;    // 2 x 4 waves, wave tile 64x128

  // A gll addressing: LDS chunk c (1024 chunks of 16B) -> row r = c>>3, slot
  // s = c&7. LDS slot s holds global slot s ^ (r&7)  (full 8-way involution;
  // frag reads land 2 lanes/bank = conflict-free).
  const int a_c0 = tid, a_c1 = 512 + tid;
  const int a_r0 = a_c0 >> 3, a_r1 = a_c1 >> 3;
  const int a_h0 = (a_c0 & 7) ^ (a_r0 & 7);
  const int a_h1 = (a_c1 & 7) ^ (a_r1 & 7);
  const int a_goff0 = a_r0 * 4096 + a_h0 * 16;
  const int a_goff1 = a_r1 * 4096 + a_h1 * 16;
  const int a_loff0 = a_c0 * 16;
  const int a_loff1 = a_c1 * 16;
  const int b_off0 = tid * 16;
  const int b_off1 = (512 + tid) * 16;
  const int b_off2 = (1024 + tid) * 16;
  const int b_off3 = (1536 + tid) * 16;

  const f32x4 zero = {0.f, 0.f, 0.f, 0.f};
  f32x4 acc[4][8];
#pragma unroll
  for (int i = 0; i < 4; ++i)
#pragma unroll
    for (int j = 0; j < 8; ++j) acc[i][j] = zero;

  // ---- prologue: issue [B0 A0 B1 A1 B2 A2], drain tile 0 (vmcnt 12) ----
  {
    gll16(wtB + b_off0, sB0 + b_off0);
    gll16(wtB + b_off1, sB0 + b_off1);
    gll16(wtB + b_off2, sB0 + b_off2);
    gll16(wtB + b_off3, sB0 + b_off3);
    gll16(encB + a_goff0, sA0 + a_loff0);
    gll16(encB + a_goff1, sA0 + a_loff1);
    const char* wb1 = wtB + 32768;
    gll16(wb1 + b_off0, sB1 + b_off0);
    gll16(wb1 + b_off1, sB1 + b_off1);
    gll16(wb1 + b_off2, sB1 + b_off2);
    gll16(wb1 + b_off3, sB1 + b_off3);
    const char* eb1 = encB + 128;
    gll16(eb1 + a_goff0, sA1 + a_loff0);
    gll16(eb1 + a_goff1, sA1 + a_loff1);
    const char* wb2 = wtB + 2 * 32768;
    gll16(wb2 + b_off0, sB2 + b_off0);
    gll16(wb2 + b_off1, sB2 + b_off1);
    gll16(wb2 + b_off2, sB2 + b_off2);
    gll16(wb2 + b_off3, sB2 + b_off3);
    const char* eb2 = encB + 256;
    gll16(eb2 + a_goff0, sA2 + a_loff0);
    gll16(eb2 + a_goff1, sA2 + a_loff1);
    asm volatile("s_waitcnt vmcnt(12)" ::: "memory");
    __builtin_amdgcn_sched_barrier(0);
    __builtin_amdgcn_s_barrier();
  }

  // main loop: iters 0..26 (always-full guards), buffers cycle mod 3
  for (int t = 0; t < 27; t += 3) {
    ITER(sA0, sB0, t, 12)
    ITER(sA1, sB1, t + 1, 12)
    ITER(sA2, sB2, t + 2, 12)
  }
  // tail: 27(full), 28(full), 29(no issue, 6), 30(0), 31(0)
  ITER(sA0, sB0, 27, 12)
  ITER(sA1, sB1, 28, 12)
  ITER(sA2, sB2, 29, 6)
  ITER(sA0, sB0, 30, 0)
  ITER(sA1, sB1, 31, 0)

  // ---- epilogue: score_row += tanh(acc + t2[col]) * v[col] ----
  float t2v[8], vv[8];
#pragma unroll
  for (int ni = 0; ni < 8; ++ni) {
    int c = wx * 128 + ni * 16 + (lane & 15);
    t2v[ni] = t2[b * Aa + c];
    vv[ni] = v[c];
  }
  float sp[4][4];
#pragma unroll
  for (int mi = 0; mi < 4; ++mi)
#pragma unroll
    for (int j = 0; j < 4; ++j) sp[mi][j] = 0.f;
#pragma unroll
  for (int mi = 0; mi < 4; ++mi)
#pragma unroll
    for (int ni = 0; ni < 8; ++ni)
#pragma unroll
      for (int j = 0; j < 4; ++j) {
        float x = acc[mi][ni][j] + t2v[ni];
        sp[mi][j] += vv[ni] * tanh_fast(x);
      }

  // C/D layout: col = lane&15, row = (lane>>4)*4 + j. Reduce over 16 col-lanes.
  float* sbuf = (float*)lds;
#pragma unroll
  for (int mi = 0; mi < 4; ++mi)
#pragma unroll
    for (int j = 0; j < 4; ++j) {
      float s = sp[mi][j];
      s += __shfl_xor(s, 1);
      s += __shfl_xor(s, 2);
      s += __shfl_xor(s, 4);
      s += __shfl_xor(s, 8);
      if ((lane & 15) == 0) {
        int r = wy * 64 + mi * 16 + ((lane >> 4) << 2) + j;
        sbuf[r * 4 + wx] = s;
      }
    }
  __syncthreads();
  if (tid < BM) {
    float s = sbuf[tid * 4] + sbuf[tid * 4 + 1] + sbuf[tid * 4 + 2] + sbuf[tid * 4 + 3];
    score[b * Ss + sc * BM + tid] = s;
  }
}

// ---- softmax over S, in place in d_out's attention region ----
__global__ __launch_bounds__(256) void softmax_k(float* __restrict__ aw) {
  const int b = blockIdx.x, t = threadIdx.x;
  __shared__ float red[8];
  float s[8];
  float m = -3.4e38f;
#pragma unroll
  for (int i = 0; i < 8; ++i) {
    s[i] = aw[b * Ss + t + i * 256];
    m = fmaxf(m, s[i]);
  }
#pragma unroll
  for (int off = 1; off < 64; off <<= 1) m = fmaxf(m, __shfl_xor(m, off));
  const int lane = t & 63, wv = t >> 6;
  if (lane == 0) red[wv] = m;
  __syncthreads();
  m = fmaxf(fmaxf(red[0], red[1]), fmaxf(red[2], red[3]));
  float e[8];
  float l = 0.f;
#pragma unroll
  for (int i = 0; i < 8; ++i) { e[i] = __expf(s[i] - m); l += e[i]; }
#pragma unroll
  for (int off = 1; off < 64; off <<= 1) l += __shfl_xor(l, off);
  if (lane == 0) red[4 + wv] = l;
  __syncthreads();
  l = red[4] + red[5] + red[6] + red[7];
  const float inv = 1.f / l;
#pragma unroll
  for (int i = 0; i < 8; ++i) aw[b * Ss + t + i * 256] = e[i] * inv;
}

// ---- context = sum_s aw[s] * enc[b,s,:] ----
__global__ __launch_bounds__(256) void ctx_partial(const float* __restrict__ enc,
                                                   const float* __restrict__ aw,
                                                   float* __restrict__ part) {
  const int b = blockIdx.x, ch = blockIdx.y, t = threadIdx.x;  // (32, 32)
  __shared__ float sw[64];
  const int s0 = ch * 64;
  if (t < 64) sw[t] = aw[b * Ss + s0 + t];
  __syncthreads();
  float ax = 0.f, ay = 0.f, az = 0.f, aww = 0.f;
  const float* ebase = enc + (size_t)(b * Ss + s0) * Kk + t * 4;
#pragma unroll 4
  for (int r = 0; r < 64; ++r) {
    const float4 ev = *(const float4*)(ebase + (size_t)r * Kk);
    const float w = sw[r];
    ax += w * ev.x; ay += w * ev.y; az += w * ev.z; aww += w * ev.w;
  }
  float4 o; o.x = ax; o.y = ay; o.z = az; o.w = aww;
  *(float4*)(part + (size_t)(b * 32 + ch) * Kk + t * 4) = o;
}

__global__ __launch_bounds__(256) void ctx_reduce(const float* __restrict__ part,
                                                  float* __restrict__ ctx) {
  const int idx = blockIdx.x * 256 + threadIdx.x;   // 32768
  const int b = idx >> 10, e = idx & 1023;
  float s = 0.f;
#pragma unroll
  for (int ch = 0; ch < 32; ++ch) s += part[(size_t)(b * 32 + ch) * Kk + e];
  ctx[idx] = s;
}

extern "C" void kernel_launch(void* const* d_in, const int* in_sizes, int n_in,
                              void* d_out, int out_size, void* d_ws, size_t ws_size,
                              hipStream_t stream) {
  const float* dh  = (const float*)d_in[0];   // (2, 32, 512)
  const float* enc = (const float*)d_in[1];   // (32, 2048, 1024)
  const float* W   = (const float*)d_in[2];   // (1024, 512)
  const float* U   = (const float*)d_in[3];   // (1024, 512)
  const float* v   = (const float*)d_in[4];   // (512, 1)

  float* out_ctx = (float*)d_out;             // (32, 1, 1024) = 32768
  float* out_aw  = (float*)d_out + 32768;     // (32, 2048)    = 65536

  char* ws = (char*)d_ws;
  unsigned short* WtT = (unsigned short*)ws;                // 1 MB (octet-major)
  float* t2p   = (float*)(ws + 1048576);                    // 512 KB
  float* t2    = (float*)(ws + 1048576 + 524288);           // 64 KB
  float* cpart = (float*)(ws + 1048576 + 524288 + 65536);   // 4 MB

  prep_wt<<<256, 256, 0, stream>>>(W, WtT);
  t2_partial<<<dim3(32, 8), 256, 0, stream>>>(dh, U, t2p);
  t2_reduce<<<64, 256, 0, stream>>>(t2p, t2);
  score_gemm<<<512, 512, 0, stream>>>(enc, WtT, t2, v, out_aw);
  softmax_k<<<32, 256, 0, stream>>>(out_aw);
  ctx_partial<<<dim3(32, 32), 256, 0, stream>>>(enc, out_aw, cpart);
  ctx_reduce<<<128, 256, 0, stream>>>(cpart, out_ctx);
}